// Round 1
// baseline (1316.212 us; speedup 1.0000x reference)
//
#include <hip/hip_runtime.h>
#include <stdint.h>

#define TOKENS 4096
#define DM 2048
#define NEXP 8
#define HSHARED 8192
#define HR 1024
#define BM 128
#define BN 128
#define BK 32

typedef __attribute__((ext_vector_type(8))) short bf16x8;
typedef __attribute__((ext_vector_type(4))) float f32x4;

__device__ __forceinline__ void gload_lds16(const void* g, void* l) {
  __builtin_amdgcn_global_load_lds((const __attribute__((address_space(1))) void*)g,
                                   (__attribute__((address_space(3))) void*)l, 16, 0, 0);
}
__device__ __forceinline__ unsigned short f2bf(float f) {
  union { float f; uint32_t u; } v; v.f = f;
  uint32_t r = (v.u + 0x7fffu + ((v.u >> 16) & 1u)) >> 16;
  return (unsigned short)r;
}
__device__ __forceinline__ float siluf(float x) { return x / (1.f + __expf(-x)); }

// ---------------- fp32 -> bf16 conversion ----------------
__global__ void cvt_kernel(const float* __restrict__ s, unsigned short* __restrict__ d, int n4) {
  int i = blockIdx.x * blockDim.x + threadIdx.x;
  int stride = gridDim.x * blockDim.x;
  for (; i < n4; i += stride) {
    float4 v = ((const float4*)s)[i];
    ushort4 o;
    o.x = f2bf(v.x); o.y = f2bf(v.y); o.z = f2bf(v.z); o.w = f2bf(v.w);
    ((ushort4*)d)[i] = o;
  }
}

// ---------------- router: sigmoid scores, top-2, counts ----------------
__global__ __launch_bounds__(256) void router_kernel(
    const float* __restrict__ x, const float* __restrict__ rw,
    const float* __restrict__ bias, int* __restrict__ counts,
    int* __restrict__ tope, float* __restrict__ topw) {
  int lane = threadIdx.x & 63, wid = threadIdx.x >> 6;
  int t = blockIdx.x * 4 + wid;
  const float* xr = x + (size_t)t * DM;
  float p[NEXP];
#pragma unroll
  for (int e = 0; e < NEXP; ++e) p[e] = 0.f;
  for (int d = lane; d < DM; d += 64) {
    float xv = xr[d];
#pragma unroll
    for (int e = 0; e < NEXP; ++e) p[e] += xv * rw[e * DM + d];
  }
#pragma unroll
  for (int e = 0; e < NEXP; ++e)
    for (int off = 32; off; off >>= 1) p[e] += __shfl_xor(p[e], off);
  if (lane == 0) {
    float sc[NEXP], sel[NEXP];
#pragma unroll
    for (int e = 0; e < NEXP; ++e) {
      sc[e] = 1.f / (1.f + __expf(-p[e]));
      sel[e] = sc[e] + bias[e];
    }
    int e0 = 0;
#pragma unroll
    for (int e = 1; e < NEXP; ++e) if (sel[e] > sel[e0]) e0 = e;
    int e1 = -1;
#pragma unroll
    for (int e = 0; e < NEXP; ++e) if (e != e0 && (e1 < 0 || sel[e] > sel[e1])) e1 = e;
    float s0 = sc[e0], s1 = sc[e1];
    float dn = s0 + s1 + 1e-9f;
    tope[2 * t] = e0; tope[2 * t + 1] = e1;
    topw[2 * t] = s0 / dn; topw[2 * t + 1] = s1 / dn;
    atomicAdd(&counts[e0], 1);
    atomicAdd(&counts[e1], 1);
  }
}

// ---------------- offsets (padded prefix sum over 8 experts) ----------------
__global__ void offsets_kernel(const int* __restrict__ counts, int* __restrict__ base,
                               int* __restrict__ padcnt) {
  if (threadIdx.x == 0) {
    int b = 0;
    for (int e = 0; e < NEXP; ++e) {
      base[e] = b;
      int pc = (counts[e] + 127) & ~127;
      padcnt[e] = pc;
      b += pc;
    }
  }
}

// ---------------- scatter token ids / weights into per-expert buckets ----------------
__global__ __launch_bounds__(256) void scatter_kernel(
    const int* __restrict__ tope, const float* __restrict__ topw,
    const int* __restrict__ base, int* __restrict__ fill,
    int* __restrict__ tlist, float* __restrict__ wlist) {
  int t = blockIdx.x * blockDim.x + threadIdx.x;
  if (t >= TOKENS) return;
#pragma unroll
  for (int k = 0; k < 2; ++k) {
    int e = tope[2 * t + k];
    int p = base[e] + atomicAdd(&fill[e], 1);
    tlist[p] = t;
    wlist[p] = topw[2 * t + k];
  }
}

// ---------------- shared expert GEMM1 (dual-B fused SwiGLU) ----------------
// h[t,j] = silu(x@sw1^T) * (x@sw2^T), written bf16, ld=HSHARED
__global__ __launch_bounds__(256, 2) void gemm_swiglu_shared(
    const unsigned short* __restrict__ A, const unsigned short* __restrict__ B1s,
    const unsigned short* __restrict__ B2s, unsigned short* __restrict__ H) {
  __shared__ unsigned short lA[BM * BK], lB1[BN * BK], lB2[BN * BK];
  const int K = DM;
  int lane = threadIdx.x & 63, wid = threadIdx.x >> 6;
  int row0 = blockIdx.y * BM, col0 = blockIdx.x * BN;
  int r = lane >> 2, cs = (lane & 3) * 8;
  int ar0 = row0 + wid * 16 + r, ar1 = ar0 + 64;
  int br0 = col0 + wid * 16 + r, br1 = br0 + 64;
  int wr = wid >> 1, wc = wid & 1;
  int fr = lane & 15, fq = lane >> 4;
  f32x4 acc1[4][4], acc2[4][4];
#pragma unroll
  for (int m = 0; m < 4; ++m)
#pragma unroll
    for (int n = 0; n < 4; ++n) { acc1[m][n] = 0.f; acc2[m][n] = 0.f; }
  for (int k0 = 0; k0 < K; k0 += BK) {
    gload_lds16(A + (size_t)ar0 * K + k0 + cs, lA + wid * 512);
    gload_lds16(A + (size_t)ar1 * K + k0 + cs, lA + (wid + 4) * 512);
    gload_lds16(B1s + (size_t)br0 * K + k0 + cs, lB1 + wid * 512);
    gload_lds16(B1s + (size_t)br1 * K + k0 + cs, lB1 + (wid + 4) * 512);
    gload_lds16(B2s + (size_t)br0 * K + k0 + cs, lB2 + wid * 512);
    gload_lds16(B2s + (size_t)br1 * K + k0 + cs, lB2 + (wid + 4) * 512);
    __syncthreads();
    bf16x8 a[4];
#pragma unroll
    for (int m = 0; m < 4; ++m)
      a[m] = *(const bf16x8*)(lA + (wr * 64 + m * 16 + fr) * BK + fq * 8);
#pragma unroll
    for (int n = 0; n < 4; ++n) {
      bf16x8 b1 = *(const bf16x8*)(lB1 + (wc * 64 + n * 16 + fr) * BK + fq * 8);
      bf16x8 b2 = *(const bf16x8*)(lB2 + (wc * 64 + n * 16 + fr) * BK + fq * 8);
#pragma unroll
      for (int m = 0; m < 4; ++m) {
        acc1[m][n] = __builtin_amdgcn_mfma_f32_16x16x32_bf16(a[m], b1, acc1[m][n], 0, 0, 0);
        acc2[m][n] = __builtin_amdgcn_mfma_f32_16x16x32_bf16(a[m], b2, acc2[m][n], 0, 0, 0);
      }
    }
    __syncthreads();
  }
#pragma unroll
  for (int m = 0; m < 4; ++m)
#pragma unroll
    for (int n = 0; n < 4; ++n)
#pragma unroll
      for (int b = 0; b < 4; ++b) {
        int rr = row0 + wr * 64 + m * 16 + fq * 4 + b;
        int cc = col0 + wc * 64 + n * 16 + fr;
        H[(size_t)rr * HSHARED + cc] = f2bf(siluf(acc1[m][n][b]) * acc2[m][n][b]);
      }
}

// ---------------- shared expert GEMM2: out = h @ sw3^T (plain fp32 store) ----------------
__global__ __launch_bounds__(256, 2) void gemm2_shared(
    const unsigned short* __restrict__ A, const unsigned short* __restrict__ Bm,
    float* __restrict__ out) {
  __shared__ unsigned short lA[BM * BK], lB[BN * BK];
  const int K = HSHARED;
  int lane = threadIdx.x & 63, wid = threadIdx.x >> 6;
  int row0 = blockIdx.y * BM, col0 = blockIdx.x * BN;
  int r = lane >> 2, cs = (lane & 3) * 8;
  int ar0 = row0 + wid * 16 + r, ar1 = ar0 + 64;
  int br0 = col0 + wid * 16 + r, br1 = br0 + 64;
  int wr = wid >> 1, wc = wid & 1;
  int fr = lane & 15, fq = lane >> 4;
  f32x4 acc[4][4];
#pragma unroll
  for (int m = 0; m < 4; ++m)
#pragma unroll
    for (int n = 0; n < 4; ++n) acc[m][n] = 0.f;
  for (int k0 = 0; k0 < K; k0 += BK) {
    gload_lds16(A + (size_t)ar0 * K + k0 + cs, lA + wid * 512);
    gload_lds16(A + (size_t)ar1 * K + k0 + cs, lA + (wid + 4) * 512);
    gload_lds16(Bm + (size_t)br0 * K + k0 + cs, lB + wid * 512);
    gload_lds16(Bm + (size_t)br1 * K + k0 + cs, lB + (wid + 4) * 512);
    __syncthreads();
    bf16x8 a[4];
#pragma unroll
    for (int m = 0; m < 4; ++m)
      a[m] = *(const bf16x8*)(lA + (wr * 64 + m * 16 + fr) * BK + fq * 8);
#pragma unroll
    for (int n = 0; n < 4; ++n) {
      bf16x8 b = *(const bf16x8*)(lB + (wc * 64 + n * 16 + fr) * BK + fq * 8);
#pragma unroll
      for (int m = 0; m < 4; ++m)
        acc[m][n] = __builtin_amdgcn_mfma_f32_16x16x32_bf16(a[m], b, acc[m][n], 0, 0, 0);
    }
    __syncthreads();
  }
#pragma unroll
  for (int m = 0; m < 4; ++m)
#pragma unroll
    for (int n = 0; n < 4; ++n)
#pragma unroll
      for (int b = 0; b < 4; ++b) {
        int rr = row0 + wr * 64 + m * 16 + fq * 4 + b;
        int cc = col0 + wc * 64 + n * 16 + fr;
        out[(size_t)rr * DM + cc] = acc[m][n][b];
      }
}

// ---------------- routed GEMM1 (gathered rows, dual-B fused SwiGLU) ----------------
__global__ __launch_bounds__(256, 2) void gemm_swiglu_routed(
    const unsigned short* __restrict__ Xbf, const unsigned short* __restrict__ W12,
    unsigned short* __restrict__ Her, const int* __restrict__ tlist,
    const int* __restrict__ base, const int* __restrict__ padcnt) {
  int e = blockIdx.z;
  int row0 = blockIdx.y * BM;
  if (row0 >= padcnt[e]) return;
  __shared__ unsigned short lA[BM * BK], lB1[BN * BK], lB2[BN * BK];
  const int K = DM;
  int col0 = blockIdx.x * BN;
  int pb = base[e];
  const unsigned short* B1s = W12 + (size_t)e * (2 * HR) * K;
  const unsigned short* B2s = B1s + (size_t)HR * K;
  int lane = threadIdx.x & 63, wid = threadIdx.x >> 6;
  int r = lane >> 2, cs = (lane & 3) * 8;
  int gr0 = tlist[pb + row0 + wid * 16 + r];
  int gr1 = tlist[pb + row0 + (wid + 4) * 16 + r];
  int br0 = col0 + wid * 16 + r, br1 = br0 + 64;
  int wr = wid >> 1, wc = wid & 1;
  int fr = lane & 15, fq = lane >> 4;
  f32x4 acc1[4][4], acc2[4][4];
#pragma unroll
  for (int m = 0; m < 4; ++m)
#pragma unroll
    for (int n = 0; n < 4; ++n) { acc1[m][n] = 0.f; acc2[m][n] = 0.f; }
  for (int k0 = 0; k0 < K; k0 += BK) {
    gload_lds16(Xbf + (size_t)gr0 * K + k0 + cs, lA + wid * 512);
    gload_lds16(Xbf + (size_t)gr1 * K + k0 + cs, lA + (wid + 4) * 512);
    gload_lds16(B1s + (size_t)br0 * K + k0 + cs, lB1 + wid * 512);
    gload_lds16(B1s + (size_t)br1 * K + k0 + cs, lB1 + (wid + 4) * 512);
    gload_lds16(B2s + (size_t)br0 * K + k0 + cs, lB2 + wid * 512);
    gload_lds16(B2s + (size_t)br1 * K + k0 + cs, lB2 + (wid + 4) * 512);
    __syncthreads();
    bf16x8 a[4];
#pragma unroll
    for (int m = 0; m < 4; ++m)
      a[m] = *(const bf16x8*)(lA + (wr * 64 + m * 16 + fr) * BK + fq * 8);
#pragma unroll
    for (int n = 0; n < 4; ++n) {
      bf16x8 b1 = *(const bf16x8*)(lB1 + (wc * 64 + n * 16 + fr) * BK + fq * 8);
      bf16x8 b2 = *(const bf16x8*)(lB2 + (wc * 64 + n * 16 + fr) * BK + fq * 8);
#pragma unroll
      for (int m = 0; m < 4; ++m) {
        acc1[m][n] = __builtin_amdgcn_mfma_f32_16x16x32_bf16(a[m], b1, acc1[m][n], 0, 0, 0);
        acc2[m][n] = __builtin_amdgcn_mfma_f32_16x16x32_bf16(a[m], b2, acc2[m][n], 0, 0, 0);
      }
    }
    __syncthreads();
  }
#pragma unroll
  for (int m = 0; m < 4; ++m)
#pragma unroll
    for (int n = 0; n < 4; ++n)
#pragma unroll
      for (int b = 0; b < 4; ++b) {
        int rloc = row0 + wr * 64 + m * 16 + fq * 4 + b;
        int cc = col0 + wc * 64 + n * 16 + fr;
        Her[(size_t)(pb + rloc) * HR + cc] = f2bf(siluf(acc1[m][n][b]) * acc2[m][n][b]);
      }
}

// ---------------- routed GEMM2: out_e @ w3^T, weighted atomic scatter-add ----------------
__global__ __launch_bounds__(256, 2) void gemm2_routed(
    const unsigned short* __restrict__ Her, const unsigned short* __restrict__ W3,
    float* __restrict__ out, const int* __restrict__ tlist, const float* __restrict__ wlist,
    const int* __restrict__ base, const int* __restrict__ padcnt,
    const int* __restrict__ counts) {
  int e = blockIdx.z;
  int row0 = blockIdx.y * BM;
  if (row0 >= padcnt[e]) return;
  __shared__ unsigned short lA[BM * BK], lB[BN * BK];
  const int K = HR;
  int col0 = blockIdx.x * BN;
  int pb = base[e];
  int cnt = counts[e];
  const unsigned short* Bm = W3 + (size_t)e * DM * HR;
  int lane = threadIdx.x & 63, wid = threadIdx.x >> 6;
  int r = lane >> 2, cs = (lane & 3) * 8;
  int ar0 = pb + row0 + wid * 16 + r, ar1 = ar0 + 64;
  int br0 = col0 + wid * 16 + r, br1 = br0 + 64;
  int wr = wid >> 1, wc = wid & 1;
  int fr = lane & 15, fq = lane >> 4;
  f32x4 acc[4][4];
#pragma unroll
  for (int m = 0; m < 4; ++m)
#pragma unroll
    for (int n = 0; n < 4; ++n) acc[m][n] = 0.f;
  for (int k0 = 0; k0 < K; k0 += BK) {
    gload_lds16(Her + (size_t)ar0 * K + k0 + cs, lA + wid * 512);
    gload_lds16(Her + (size_t)ar1 * K + k0 + cs, lA + (wid + 4) * 512);
    gload_lds16(Bm + (size_t)br0 * K + k0 + cs, lB + wid * 512);
    gload_lds16(Bm + (size_t)br1 * K + k0 + cs, lB + (wid + 4) * 512);
    __syncthreads();
    bf16x8 a[4];
#pragma unroll
    for (int m = 0; m < 4; ++m)
      a[m] = *(const bf16x8*)(lA + (wr * 64 + m * 16 + fr) * BK + fq * 8);
#pragma unroll
    for (int n = 0; n < 4; ++n) {
      bf16x8 b = *(const bf16x8*)(lB + (wc * 64 + n * 16 + fr) * BK + fq * 8);
#pragma unroll
      for (int m = 0; m < 4; ++m)
        acc[m][n] = __builtin_amdgcn_mfma_f32_16x16x32_bf16(a[m], b, acc[m][n], 0, 0, 0);
    }
    __syncthreads();
  }
#pragma unroll
  for (int m = 0; m < 4; ++m)
#pragma unroll
    for (int b = 0; b < 4; ++b) {
      int rloc = row0 + wr * 64 + m * 16 + fq * 4 + b;
      if (rloc < cnt) {
        int t = tlist[pb + rloc];
        float wgt = wlist[pb + rloc];
#pragma unroll
        for (int n = 0; n < 4; ++n) {
          int cc = col0 + wc * 64 + n * 16 + fr;
          atomicAdd(&out[(size_t)t * DM + cc], wgt * acc[m][n][b]);
        }
      }
    }
}

// ---------------- launch ----------------
extern "C" void kernel_launch(void* const* d_in, const int* in_sizes, int n_in,
                              void* d_out, int out_size, void* d_ws, size_t ws_size,
                              hipStream_t stream) {
  const float* x = (const float*)d_in[0];
  const float* w12 = (const float*)d_in[1];
  const float* w3 = (const float*)d_in[2];
  const float* rw = (const float*)d_in[3];
  const float* bias = (const float*)d_in[4];
  const float* sw1 = (const float*)d_in[5];
  const float* sw2 = (const float*)d_in[6];
  const float* sw3 = (const float*)d_in[7];
  float* out = (float*)d_out;

  size_t off = 0;
  char* ws = (char*)d_ws;
  auto alloc = [&](size_t bytes) -> void* {
    void* p = ws + off;
    off += (bytes + 255) & ~(size_t)255;
    return p;
  };
  unsigned short* xbf  = (unsigned short*)alloc((size_t)TOKENS * DM * 2);
  unsigned short* sw1b = (unsigned short*)alloc((size_t)HSHARED * DM * 2);
  unsigned short* sw2b = (unsigned short*)alloc((size_t)HSHARED * DM * 2);
  unsigned short* sw3b = (unsigned short*)alloc((size_t)DM * HSHARED * 2);
  unsigned short* w12b = (unsigned short*)alloc((size_t)NEXP * 2 * HR * DM * 2);
  unsigned short* w3b  = (unsigned short*)alloc((size_t)NEXP * DM * HR * 2);
  unsigned short* hsh  = (unsigned short*)alloc((size_t)TOKENS * HSHARED * 2);
  unsigned short* her  = (unsigned short*)alloc((size_t)9216 * HR * 2);
  int* ctrl = (int*)alloc((size_t)(32 + 9216 + 9216 + 8192 + 8192) * 4);
  int* counts = ctrl;
  int* fill = ctrl + 8;
  int* base = ctrl + 16;
  int* padcnt = ctrl + 24;
  int* tlist = ctrl + 32;
  float* wlist = (float*)(ctrl + 32 + 9216);
  int* tope = ctrl + 32 + 9216 + 9216;
  float* topw = (float*)(ctrl + 32 + 9216 + 9216 + 8192);

  // zero counts/fill/base/padcnt/tlist (padding entries must be token 0)
  hipMemsetAsync(ctrl, 0, (size_t)(32 + 9216) * 4, stream);

  // fp32 -> bf16 conversions
  cvt_kernel<<<2048, 256, 0, stream>>>(x, xbf, TOKENS * DM / 4);
  cvt_kernel<<<2048, 256, 0, stream>>>(sw1, sw1b, HSHARED * DM / 4);
  cvt_kernel<<<2048, 256, 0, stream>>>(sw2, sw2b, HSHARED * DM / 4);
  cvt_kernel<<<2048, 256, 0, stream>>>(sw3, sw3b, DM * HSHARED / 4);
  cvt_kernel<<<2048, 256, 0, stream>>>(w12, w12b, NEXP * 2 * HR * DM / 4);
  cvt_kernel<<<2048, 256, 0, stream>>>(w3, w3b, NEXP * DM * HR / 4);

  // routing
  router_kernel<<<TOKENS / 4, 256, 0, stream>>>(x, rw, bias, counts, tope, topw);
  offsets_kernel<<<1, 64, 0, stream>>>(counts, base, padcnt);
  scatter_kernel<<<TOKENS / 256, 256, 0, stream>>>(tope, topw, base, fill, tlist, wlist);

  // shared expert
  gemm_swiglu_shared<<<dim3(HSHARED / BN, TOKENS / BM), 256, 0, stream>>>(xbf, sw1b, sw2b, hsh);
  gemm2_shared<<<dim3(DM / BN, TOKENS / BM), 256, 0, stream>>>(hsh, sw3b, out);

  // routed experts (worst-case grid, early-exit on padded count)
  gemm_swiglu_routed<<<dim3(HR / BN, TOKENS / BM, NEXP), 256, 0, stream>>>(
      xbf, w12b, her, tlist, base, padcnt);
  gemm2_routed<<<dim3(DM / BN, TOKENS / BM, NEXP), 256, 0, stream>>>(
      her, w3b, out, tlist, wlist, base, padcnt, counts);
}